// Round 7
// baseline (248.107 us; speedup 1.0000x reference)
//
// DANet dual-attention block, MI355X/gfx950.
// R7 = R6 with __exp2f -> __builtin_amdgcn_exp2f (device exp2):
//  - V global->register (coalesced 16x64B), prefetched 1 step ahead; Vlds gone
//  - P dbuf -> ONE s_barrier per m-step
//  - 2-wave blocks (c-quarter): 4 independent barrier groups per CU
//  - exp2 with log2e folded into Qt (QKV epilogue)
//  - CA-out epilogue register-direct, barrier-free
#include <hip/hip_runtime.h>

#define CH   512
#define NPIX 4096
#define CQ   32
#define MR   640   // 512 (wv) + 32 (wq) + 32 (wk) + 64 zero pad
#define NB   4
#define LOG2E 1.44269504088896340736f

typedef unsigned short u16;
typedef __bf16 bf16x8 __attribute__((ext_vector_type(8)));
typedef float  f32x4  __attribute__((ext_vector_type(4)));
typedef unsigned int uint4v __attribute__((ext_vector_type(4)));
typedef unsigned int uint2v __attribute__((ext_vector_type(2)));

__device__ __forceinline__ u16 f2bf(float f) {
  union { float f; unsigned int u; } v; v.f = f;
  unsigned int r = v.u + 0x7FFFu + ((v.u >> 16) & 1u);   // RNE
  return (u16)(r >> 16);
}

__device__ __forceinline__ float exp2fast(float f) {
  return __builtin_amdgcn_exp2f(f);      // v_exp_f32: D = 2^S0
}

__device__ __forceinline__ void gload_lds16(const u16* g, u16* l) {
  __builtin_amdgcn_global_load_lds(
      (const __attribute__((address_space(1))) unsigned int*)g,
      (__attribute__((address_space(3))) unsigned int*)l, 16, 0, 0);
}

__device__ __forceinline__ int xcd_swz(int flat, int nwg) {
  if (nwg & 7) return flat;
  return (flat & 7) * (nwg >> 3) + (flat >> 3);
}

// ---------------- weight stack: Wb[640][512] bf16, biasS[640] ----------------
__global__ void k_prep_w(const float* __restrict__ wq, const float* __restrict__ bq,
                         const float* __restrict__ wk, const float* __restrict__ bk,
                         const float* __restrict__ wv, const float* __restrict__ bv,
                         u16* __restrict__ Wb, float* __restrict__ biasS) {
  int idx = blockIdx.x * 256 + threadIdx.x;
  if (idx < MR * CH) {
    int r = idx >> 9, c = idx & 511;
    float v = 0.f;
    if (r < 512)      v = wv[r * CH + c];
    else if (r < 544) v = wq[(r - 512) * CH + c];
    else if (r < 576) v = wk[(r - 544) * CH + c];
    Wb[idx] = f2bf(v);
  }
  if (idx < MR) {
    float v = 0.f;
    if (idx < 512)      v = bv[idx];
    else if (idx < 544) v = bq[idx - 512];
    else if (idx < 576) v = bk[idx - 544];
    biasS[idx] = v;
  }
}

// ------------- x -> Xb bf16 [B][512][4096], Xt bf16 [B][4096][512] -----------
__global__ __launch_bounds__(256) void k_convert(const float* __restrict__ x,
                                                 u16* __restrict__ Xb,
                                                 u16* __restrict__ Xt) {
  __shared__ float tile[64][65];
  const int b = blockIdx.z, ct = blockIdx.y, nt = blockIdx.x;
  const int t = threadIdx.x, tn = t & 63, tg = t >> 6;
  const size_t xbase = ((size_t)b * CH + ct * 64) * NPIX + nt * 64;
#pragma unroll
  for (int i = 0; i < 16; ++i) {
    int cl = tg * 16 + i;
    float v = x[xbase + (size_t)cl * NPIX + tn];
    Xb[xbase + (size_t)cl * NPIX + tn] = f2bf(v);
    tile[cl][tn] = v;
  }
  __syncthreads();
  const size_t tbase = ((size_t)b * NPIX + nt * 64) * CH + ct * 64;
#pragma unroll
  for (int i = 0; i < 16; ++i) {
    int nl = tg * 16 + i;
    Xt[tbase + (size_t)nl * CH + tn] = f2bf(tile[tn][nl]);
  }
}

// --------------------------- generic NT bf16 GEMM ----------------------------
enum { EP_QKV = 0, EP_PART = 1 };

template <int EP>
__global__ __launch_bounds__(256) void gemm_nt(
    const u16* __restrict__ Aall, const u16* __restrict__ Ball,
    long sA, long sB, int K, int ld, int zBase,
    void* pa0, void* pa1, void* pa2, const float* pg) {
  __shared__ u16 Alds[128 * 32];
  __shared__ u16 Blds[128 * 32];
  const int nbx = gridDim.x, nby = gridDim.y;
  const int nwg = nbx * nby * gridDim.z;
  int flat = blockIdx.x + nbx * (blockIdx.y + nby * blockIdx.z);
  flat = xcd_swz(flat, nwg);
  const int bx = flat % nbx, by = (flat / nbx) % nby, bz = flat / (nbx * nby);

  const int t = threadIdx.x, l = t & 63, w = t >> 6;
  const int wr = w >> 1, wc = w & 1;
  size_t aoff, boff;
  if constexpr (EP == EP_PART) {           // bz = b*4 + kslice
    aoff = (size_t)(bz >> 2) * sA + (size_t)(bz & 3) * 1024;
    boff = (size_t)(bz >> 2) * sB + (size_t)(bz & 3) * 1024;
  } else {
    aoff = (size_t)bz * sA;
    boff = (size_t)bz * sB;
  }
  const u16* A = Aall + aoff;
  const u16* B = Ball + boff;
  const int rowBase = bx * 128, colBase = by * 128;

  f32x4 acc[4][4];
#pragma unroll
  for (int i = 0; i < 4; ++i)
#pragma unroll
    for (int j = 0; j < 4; ++j) acc[i][j] = f32x4{0.f, 0.f, 0.f, 0.f};

  const int rs0 = l >> 2, cs0 = (l & 3) * 8;

  for (int k0 = 0; k0 < K; k0 += 32) {
    __syncthreads();
#pragma unroll
    for (int i = 0; i < 2; ++i) {
      int chunk = w * 2 + i;
      int r = chunk * 16 + rs0;
      gload_lds16(A + (size_t)(rowBase + r) * ld + k0 + cs0, Alds + chunk * 512);
      gload_lds16(B + (size_t)(colBase + r) * ld + k0 + cs0, Blds + chunk * 512);
    }
    __syncthreads();
    bf16x8 af[4], bfr[4];
#pragma unroll
    for (int i = 0; i < 4; ++i) {
      af[i]  = *(const bf16x8*)(Alds + (wr * 64 + i * 16 + (l & 15)) * 32 + (l >> 4) * 8);
      bfr[i] = *(const bf16x8*)(Blds + (wc * 64 + i * 16 + (l & 15)) * 32 + (l >> 4) * 8);
    }
#pragma unroll
    for (int i = 0; i < 4; ++i)
#pragma unroll
      for (int j = 0; j < 4; ++j)
        acc[i][j] = __builtin_amdgcn_mfma_f32_16x16x32_bf16(af[i], bfr[j], acc[i][j], 0, 0, 0);
  }

  // D layout: col = lane&15, row = (lane>>4)*4 + reg   [m89/m91 verified]
  const int b = zBase + bz;
  if constexpr (EP == EP_QKV) {
    u16* Vb = (u16*)pa0; u16* Qt = (u16*)pa1; u16* Kt = (u16*)pa2;
#pragma unroll
    for (int i = 0; i < 4; ++i)
#pragma unroll
      for (int r = 0; r < 4; ++r) {
        int row = rowBase + wr * 64 + i * 16 + (l >> 4) * 4 + r;
        if (row >= 576) continue;
        float bias = pg[row];
        // Q rows carry log2(e) so pa_fused can use exp2 directly
        float scale = (row >= 512 && row < 544) ? LOG2E : 1.0f;
#pragma unroll
        for (int j = 0; j < 4; ++j) {
          int col = colBase + wc * 64 + j * 16 + (l & 15);
          u16 h = f2bf((acc[i][j][r] + bias) * scale);
          if (row < 512)      Vb[((size_t)b * CH + row) * NPIX + col] = h;
          else if (row < 544) Qt[((size_t)b * NPIX + col) * CQ + (row - 512)] = h;
          else                Kt[((size_t)b * NPIX + col) * CQ + (row - 544)] = h;
        }
      }
  } else {                                 // EP_PART: CA energy partial fp32
    float* C = (float*)pa0;
#pragma unroll
    for (int i = 0; i < 4; ++i)
#pragma unroll
      for (int j = 0; j < 4; ++j)
#pragma unroll
        for (int r = 0; r < 4; ++r) {
          int row = rowBase + wr * 64 + i * 16 + (l >> 4) * 4 + r;
          int col = colBase + wc * 64 + j * 16 + (l & 15);
          C[((size_t)bz * CH + row) * CH + col] = acc[i][j][r];
        }
  }
}

// ---------------- fused position attention + CA-out epilogue -----------------
// block: (batch, n-tile 64, c-quarter 128); 2 waves, wave w owns c-rows
// [cq*128 + w*64, +64) and m-halves [w*32, w*32+32) of each 64-m step.
// Per step: QK^T (8 MFMA) -> exp2 -> P dbuf write -> ONE barrier -> PV with
// V in registers (prefetched 1 step ahead, coalesced 16x64B global reads).
__global__ __launch_bounds__(128, 2) void k_pa_fused(
    const u16* __restrict__ Qt, const u16* __restrict__ Kt,
    const u16* __restrict__ Vb, const u16* __restrict__ Aca,
    const u16* __restrict__ Xt, const float* __restrict__ x,
    float* __restrict__ out, const float* __restrict__ gpa) {
  __shared__ u16 Plds[2][64 * 64];        // 16 KB total, [n][m] bf16, XOR-swz

  int flat = xcd_swz(blockIdx.x, gridDim.x);
  const int nt = flat & 63, cq = (flat >> 6) & 3, b = flat >> 8;
  const int n0 = nt * 64;
  const int l = threadIdx.x & 63, w = threadIdx.x >> 6;
  const int lo = l & 15, hi = l >> 4;
  const int c0w = cq * 128 + w * 64;

  const u16* Qtb = Qt + (size_t)b * NPIX * CQ;
  const u16* Ktb = Kt + (size_t)b * NPIX * CQ;
  const u16* Vbb = Vb + (size_t)b * CH * NPIX;
  const f32x4 zero = {0.f, 0.f, 0.f, 0.f};

  // hoisted Q fragments: all 4 n-frags (Qt already scaled by log2e)
  bf16x8 bq[4];
#pragma unroll
  for (int nf = 0; nf < 4; ++nf)
    bq[nf] = *(const bf16x8*)(Qtb + (size_t)(n0 + nf * 16 + lo) * CQ + hi * 8);

  f32x4 acc[4][4];
#pragma unroll
  for (int i = 0; i < 4; ++i)
#pragma unroll
    for (int j = 0; j < 4; ++j) acc[i][j] = zero;
  float rs[4] = {0.f, 0.f, 0.f, 0.f};

#define LDK(m, ml) (*(const bf16x8*)(Ktb + (size_t)((m) + w * 32 + (ml) * 16 + lo) * CQ + hi * 8))
#define LDV(m, i, h) (*(const bf16x8*)(Vbb + (size_t)(c0w + (i) * 16 + lo) * NPIX + (m) + (h) * 32 + hi * 8))

#define PA_STEP(Kc0, Kc1, Kn0, Kn1, Vc, Vn, X, mnext)                          \
  {                                                                            \
    f32x4 s_[4][2];                                                            \
    _Pragma("unroll")                                                          \
    for (int nf_ = 0; nf_ < 4; ++nf_) {                                        \
      s_[nf_][0] = __builtin_amdgcn_mfma_f32_16x16x32_bf16(Kc0, bq[nf_], zero, 0, 0, 0); \
      s_[nf_][1] = __builtin_amdgcn_mfma_f32_16x16x32_bf16(Kc1, bq[nf_], zero, 0, 0, 0); \
    }                                                                          \
    Kn0 = LDK(mnext, 0);                                                       \
    Kn1 = LDK(mnext, 1);                                                       \
    _Pragma("unroll")                                                          \
    for (int nf_ = 0; nf_ < 4; ++nf_) {                                        \
      int n_ = nf_ * 16 + lo;                                                  \
      char* rowp_ = (char*)(Plds[X]) + n_ * 128 + (hi & 1) * 8;                \
      _Pragma("unroll")                                                        \
      for (int ml_ = 0; ml_ < 2; ++ml_) {                                      \
        float p0_ = exp2fast(s_[nf_][ml_][0]), p1_ = exp2fast(s_[nf_][ml_][1]);\
        float p2_ = exp2fast(s_[nf_][ml_][2]), p3_ = exp2fast(s_[nf_][ml_][3]);\
        rs[nf_] += (p0_ + p1_) + (p2_ + p3_);                                  \
        unsigned int u0_, u1_;                                                 \
        asm("v_cvt_pk_bf16_f32 %0, %1, %2" : "=v"(u0_) : "v"(p0_), "v"(p1_));  \
        asm("v_cvt_pk_bf16_f32 %0, %1, %2" : "=v"(u1_) : "v"(p2_), "v"(p3_));  \
        int slot_ = w * 4 + ml_ * 2 + (hi >> 1);                               \
        *(uint2v*)(rowp_ + ((slot_ ^ (n_ & 7)) << 4)) = uint2v{u0_, u1_};      \
      }                                                                        \
    }                                                                          \
    asm volatile("s_waitcnt lgkmcnt(0)" ::: "memory");                         \
    __builtin_amdgcn_sched_barrier(0);                                         \
    __builtin_amdgcn_s_barrier();                                              \
    __builtin_amdgcn_sched_barrier(0);                                         \
    _Pragma("unroll")                                                          \
    for (int i_ = 0; i_ < 4; ++i_) {                                           \
      Vn[i_ * 2 + 0] = LDV(mnext, i_, 0);                                      \
      Vn[i_ * 2 + 1] = LDV(mnext, i_, 1);                                      \
    }                                                                          \
    __builtin_amdgcn_s_setprio(1);                                             \
    _Pragma("unroll")                                                          \
    for (int h_ = 0; h_ < 2; ++h_) {                                           \
      bf16x8 bp_[4];                                                           \
      _Pragma("unroll")                                                        \
      for (int j_ = 0; j_ < 4; ++j_) {                                         \
        int nn_ = j_ * 16 + lo;                                                \
        bp_[j_] = *(const bf16x8*)((const char*)(Plds[X]) + nn_ * 128 +        \
                                   (((h_ * 4 + hi) ^ (nn_ & 7)) << 4));        \
      }                                                                        \
      _Pragma("unroll")                                                        \
      for (int i_ = 0; i_ < 4; ++i_)                                           \
        _Pragma("unroll")                                                      \
        for (int j_ = 0; j_ < 4; ++j_)                                         \
          acc[i_][j_] = __builtin_amdgcn_mfma_f32_16x16x32_bf16(               \
              Vc[i_ * 2 + h_], bp_[j_], acc[i_][j_], 0, 0, 0);                 \
    }                                                                          \
    __builtin_amdgcn_s_setprio(0);                                             \
  }

  // prologue: K(0), V(0) into set A
  bf16x8 kA0 = LDK(0, 0), kA1 = LDK(0, 1), kB0, kB1;
  bf16x8 vA[8], vB[8];
#pragma unroll
  for (int i = 0; i < 4; ++i) {
    vA[i * 2 + 0] = LDV(0, i, 0);
    vA[i * 2 + 1] = LDV(0, i, 1);
  }

  for (int ti = 0; ti < 64; ti += 2) {
    PA_STEP(kA0, kA1, kB0, kB1, vA, vB, 0, (((ti + 1) & 63) * 64));
    PA_STEP(kB0, kB1, kA0, kA1, vB, vA, 1, (((ti + 2) & 63) * 64));
  }
#undef PA_STEP
#undef LDK
#undef LDV

  // ---- rowsum exchange across the 2 waves (reuse Plds) ----
  __syncthreads();
#pragma unroll
  for (int nf = 0; nf < 4; ++nf) {
    rs[nf] += __shfl_xor(rs[nf], 16);
    rs[nf] += __shfl_xor(rs[nf], 32);
  }
  float* rbuf = (float*)Plds;
  if (l < 16) {
#pragma unroll
    for (int nf = 0; nf < 4; ++nf) rbuf[w * 64 + nf * 16 + l] = rs[nf];
  }
  __syncthreads();
  const float gv = gpa[0];
  float rinv[4];
#pragma unroll
  for (int j = 0; j < 4; ++j)
    rinv[j] = gv / (rbuf[j * 16 + lo] + rbuf[64 + j * 16 + lo]);
#pragma unroll
  for (int i = 0; i < 4; ++i)
#pragma unroll
    for (int j = 0; j < 4; ++j) acc[i][j] *= rinv[j];

  // ---- CA-out epilogue, register-direct (no LDS, no barriers) ----
  const u16* Acab = Aca + (size_t)b * CH * CH;
  const u16* Xtb = Xt + (size_t)b * NPIX * CH;
#define LDA_CA(k0, i) (*(const bf16x8*)(Acab + (size_t)(c0w + (i) * 16 + lo) * CH + (k0) + hi * 8))
#define LDX_CA(k0, j) (*(const bf16x8*)(Xtb + (size_t)(n0 + (j) * 16 + lo) * CH + (k0) + hi * 8))
#define CA_MFMA(AF, BX)                                                        \
  _Pragma("unroll")                                                            \
  for (int i_ = 0; i_ < 4; ++i_)                                               \
    _Pragma("unroll")                                                          \
    for (int j_ = 0; j_ < 4; ++j_)                                             \
      acc[i_][j_] = __builtin_amdgcn_mfma_f32_16x16x32_bf16(AF[i_], BX[j_], acc[i_][j_], 0, 0, 0);

  bf16x8 caA[4], cxA[4], caB[4], cxB[4];
#pragma unroll
  for (int i = 0; i < 4; ++i) { caA[i] = LDA_CA(0, i); cxA[i] = LDX_CA(0, i); }
  for (int k0 = 0; k0 < CH; k0 += 64) {
#pragma unroll
    for (int i = 0; i < 4; ++i) { caB[i] = LDA_CA(k0 + 32, i); cxB[i] = LDX_CA(k0 + 32, i); }
    CA_MFMA(caA, cxA);
    int k2 = (k0 + 64) & (CH - 1);
#pragma unroll
    for (int i = 0; i < 4; ++i) { caA[i] = LDA_CA(k2, i); cxA[i] = LDX_CA(k2, i); }
    CA_MFMA(caB, cxB);
  }
#undef LDA_CA
#undef LDX_CA
#undef CA_MFMA

  // ---- final: out = acc + 2x ----
  float* outb = out + (size_t)b * CH * NPIX;
  const float* xb = x + (size_t)b * CH * NPIX;
#pragma unroll
  for (int i = 0; i < 4; ++i)
#pragma unroll
    for (int j = 0; j < 4; ++j)
#pragma unroll
      for (int r = 0; r < 4; ++r) {
        int c = c0w + i * 16 + hi * 4 + r;
        int n = n0 + j * 16 + lo;
        size_t idx = (size_t)c * NPIX + n;
        outb[idx] = acc[i][j][r] + 2.0f * xb[idx];
      }
}

// --- CA softmax: sum 4 split-K partials; Aca = gca * softmax_d(rowmax-E) -----
__global__ __launch_bounds__(256) void k_ca_softmax(const float* __restrict__ CAEp,
                                                    u16* __restrict__ Aca,
                                                    const float* __restrict__ gca) {
  const int l = threadIdx.x & 63, w = threadIdx.x >> 6;
  const int row = blockIdx.x * 4 + w;   // [0, NB*512)
  const int b = row >> 9, r = row & 511;
  float en0[8];
#pragma unroll
  for (int i = 0; i < 8; ++i) en0[i] = 0.f;
#pragma unroll
  for (int ks = 0; ks < 4; ++ks) {
    const float* e = CAEp + (((size_t)(b * 4 + ks) * CH + r) * CH);
    f32x4 a = *(const f32x4*)(e + l * 8);
    f32x4 c = *(const f32x4*)(e + l * 8 + 4);
#pragma unroll
    for (int i = 0; i < 4; ++i) { en0[i] += a[i]; en0[4 + i] += c[i]; }
  }
  float m1 = en0[0];
#pragma unroll
  for (int i = 1; i < 8; ++i) m1 = fmaxf(m1, en0[i]);
  for (int o = 1; o < 64; o <<= 1) m1 = fmaxf(m1, __shfl_xor(m1, o));
  float en[8];
#pragma unroll
  for (int i = 0; i < 8; ++i) en[i] = m1 - en0[i];
  float m2 = en[0];
#pragma unroll
  for (int i = 1; i < 8; ++i) m2 = fmaxf(m2, en[i]);
  for (int o = 1; o < 64; o <<= 1) m2 = fmaxf(m2, __shfl_xor(m2, o));
  float p[8], s = 0.f;
#pragma unroll
  for (int i = 0; i < 8; ++i) { p[i] = __expf(en[i] - m2); s += p[i]; }
  for (int o = 1; o < 64; o <<= 1) s += __shfl_xor(s, o);
  const float inv = gca[0] / s;
  union { u16 h[8]; uint4v v; } u;
#pragma unroll
  for (int i = 0; i < 8; ++i) u.h[i] = f2bf(p[i] * inv);
  *(uint4v*)(Aca + (size_t)row * CH + l * 8) = u.v;
}

// --------------------------------- host --------------------------------------
extern "C" void kernel_launch(void* const* d_in, const int* in_sizes, int n_in,
                              void* d_out, int out_size, void* d_ws, size_t ws_size,
                              hipStream_t stream) {
  const float* x   = (const float*)d_in[0];
  const float* wq  = (const float*)d_in[1];
  const float* bq  = (const float*)d_in[2];
  const float* wk  = (const float*)d_in[3];
  const float* bk  = (const float*)d_in[4];
  const float* wv  = (const float*)d_in[5];
  const float* bv  = (const float*)d_in[6];
  const float* gpa = (const float*)d_in[7];
  const float* gca = (const float*)d_in[8];
  float* out = (float*)d_out;

  char* wsp = (char*)d_ws;
  size_t off = 0;
  auto alloc = [&](size_t bytes) -> void* {
    void* p = (void*)(wsp + off);
    off = (off + bytes + 255) & ~(size_t)255;
    return p;
  };
  const size_t EB = (size_t)NB * CH * NPIX;
  u16*   Xb    = (u16*)alloc(EB * 2);
  u16*   Xt    = (u16*)alloc(EB * 2);
  u16*   Wb    = (u16*)alloc((size_t)MR * CH * 2);
  float* biasS = (float*)alloc((size_t)MR * 4);
  u16*   Vb    = (u16*)alloc(EB * 2);
  u16*   Qt    = (u16*)alloc((size_t)NB * NPIX * CQ * 2);
  u16*   Kt    = (u16*)alloc((size_t)NB * NPIX * CQ * 2);
  float* CAEp  = (float*)alloc((size_t)NB * 4 * CH * CH * 4);   // split-K partials
  u16*   Aca   = (u16*)alloc((size_t)NB * CH * CH * 2);

  k_prep_w<<<(MR * CH + 255) / 256, 256, 0, stream>>>(wq, bq, wk, bk, wv, bv, Wb, biasS);
  k_convert<<<dim3(64, 8, NB), 256, 0, stream>>>(x, Xb, Xt);

  // QKV: [640][512] x [4096][512]^T  -> Vb, Qt (pre-scaled log2e), Kt (+bias)
  gemm_nt<EP_QKV><<<dim3(MR / 128, NPIX / 128, NB), 256, 0, stream>>>(
      Wb, Xt, 0L, (long)NPIX * CH, CH, CH, 0, Vb, Qt, Kt, biasS);

  // CA energy split-K: Xb x Xb^T, K=1024 per slice -> CAEp[b*4+ks]
  gemm_nt<EP_PART><<<dim3(CH / 128, CH / 128, NB * 4), 256, 0, stream>>>(
      Xb, Xb, (long)CH * NPIX, (long)CH * NPIX, 1024, NPIX, 0,
      CAEp, nullptr, nullptr, nullptr);
  k_ca_softmax<<<NB * CH / 4, 256, 0, stream>>>(CAEp, Aca, gca);

  // fused position attention + CA epilogue -> out = gpa*PA + gca*CA + 2x
  k_pa_fused<<<NB * 4 * (NPIX / 64), 128, 0, stream>>>(
      Qt, Kt, Vb, Aca, Xt, x, out, gpa);
}